// Round 8
// baseline (19132.384 us; speedup 1.0000x reference)
//
#include <hip/hip_runtime.h>
#include <math.h>
#include <stdint.h>

#define NN 500000
#define NE 16000000
#define NTILE 62                  // dst tiles of 8192 (dst >> 13)
#define DSZ 8192
#define NQ 8                      // src octants of 62500
#define OCTW 62500
#define NCH 496                   // 62 * 8
#define PB 65536                  // edges per partition block
#define NPB ((NE + PB - 1) / PB)  // 245
#define SLOT 34112                // mean 32258, sigma~180, +10 sigma, mult of 16
#define HPST 507904               // NTILE*DSZ (>= NN)
#define NF4 125000                // NN/4

// ---------------- phase 1: partition edges into 496 fixed chunk slots -----
// chunk = (dst>>13)*8 + src/62500. word = (dst&8191)<<16 | (src - q*62500).
__global__ __launch_bounds__(1024) void partition_kernel(const int4* __restrict__ src4,
                                                         const int4* __restrict__ dst4,
                                                         int* __restrict__ bcnt,
                                                         uint32_t* __restrict__ ebuf) {
    __shared__ int lh[NCH];
    for (int i = threadIdx.x; i < NCH; i += 1024) lh[i] = 0;
    __syncthreads();
    long base4 = (long)blockIdx.x * (PB / 4);
    for (int k = 0; k < PB / 4; k += 1024) {
        long i4 = base4 + k + threadIdx.x;
        if (i4 < NE / 4) {
            int4 d = dst4[i4];
            int4 s = src4[i4];
            atomicAdd(&lh[((d.x >> 13) << 3) + s.x / OCTW], 1);
            atomicAdd(&lh[((d.y >> 13) << 3) + s.y / OCTW], 1);
            atomicAdd(&lh[((d.z >> 13) << 3) + s.z / OCTW], 1);
            atomicAdd(&lh[((d.w >> 13) << 3) + s.w / OCTW], 1);
        }
    }
    __syncthreads();
    for (int i = threadIdx.x; i < NCH; i += 1024) {
        int c = lh[i];
        if (c) lh[i] = atomicAdd(&bcnt[i], c);   // reserve run; lh = block cursor
    }
    __syncthreads();
    for (int k = 0; k < PB / 4; k += 1024) {
        long i4 = base4 + k + threadIdx.x;
        if (i4 < NE / 4) {
            int4 d = dst4[i4];
            int4 s = src4[i4];
            int q, ch, rel;
            q = s.x / OCTW; ch = ((d.x >> 13) << 3) + q; rel = atomicAdd(&lh[ch], 1);
            if (rel < SLOT) ebuf[(size_t)ch * SLOT + rel] =
                ((uint32_t)(d.x & 8191) << 16) | (uint32_t)(s.x - q * OCTW);
            q = s.y / OCTW; ch = ((d.y >> 13) << 3) + q; rel = atomicAdd(&lh[ch], 1);
            if (rel < SLOT) ebuf[(size_t)ch * SLOT + rel] =
                ((uint32_t)(d.y & 8191) << 16) | (uint32_t)(s.y - q * OCTW);
            q = s.z / OCTW; ch = ((d.z >> 13) << 3) + q; rel = atomicAdd(&lh[ch], 1);
            if (rel < SLOT) ebuf[(size_t)ch * SLOT + rel] =
                ((uint32_t)(d.z & 8191) << 16) | (uint32_t)(s.z - q * OCTW);
            q = s.w / OCTW; ch = ((d.w >> 13) << 3) + q; rel = atomicAdd(&lh[ch], 1);
            if (rel < SLOT) ebuf[(size_t)ch * SLOT + rel] =
                ((uint32_t)(d.w & 8191) << 16) | (uint32_t)(s.w - q * OCTW);
        }
    }
}

// ---------------- phase 2: tiny serial scan of 496 chunk bases ------------
__global__ void cbase_scan(const int* __restrict__ bcnt, int* __restrict__ cbase) {
    if (threadIdx.x == 0) {
        int run = 0;
        for (int c = 0; c < NCH; c++) {
            cbase[c] = run;
            int n = bcnt[c];
            run += (n > SLOT) ? SLOT : n;
        }
        cbase[NCH] = run;
    }
}

// ---------------- phase 3: per-chunk 8-bucket sort (by src subchunk) ------
// Per-wave cursor ranges -> pass2 writes are 8 sequential streams per wave.
__global__ __launch_bounds__(1024) void subsort_kernel(const int* __restrict__ bcnt,
                                                       const int* __restrict__ cbase,
                                                       const uint32_t* __restrict__ ebuf,
                                                       uint32_t* __restrict__ sorted,
                                                       int* __restrict__ sstart,
                                                       int* __restrict__ deg) {
    __shared__ int dh[DSZ];               // 32KB per-dst degree
    __shared__ int whist[16][8];
    __shared__ int wcur[16][8];
    __shared__ int bb[9];
    int c = blockIdx.x;
    long abase = (long)c * SLOT;
    int n = bcnt[c];
    if (n > SLOT) n = SLOT;
    int obase = cbase[c];
    int t = c >> 3;
    int wid = threadIdx.x >> 6;
    for (int i = threadIdx.x; i < DSZ; i += 1024) dh[i] = 0;
    if (threadIdx.x < 128) ((int*)whist)[threadIdx.x] = 0;
    __syncthreads();
    const uint4* eb4 = (const uint4*)(ebuf + abase);
    int n4 = n >> 2;
    for (int i = threadIdx.x; i < n4; i += 1024) {
        uint4 w = eb4[i];
        atomicAdd(&whist[wid][(w.x & 0xFFFFu) >> 13], 1); atomicAdd(&dh[w.x >> 16], 1);
        atomicAdd(&whist[wid][(w.y & 0xFFFFu) >> 13], 1); atomicAdd(&dh[w.y >> 16], 1);
        atomicAdd(&whist[wid][(w.z & 0xFFFFu) >> 13], 1); atomicAdd(&dh[w.z >> 16], 1);
        atomicAdd(&whist[wid][(w.w & 0xFFFFu) >> 13], 1); atomicAdd(&dh[w.w >> 16], 1);
    }
    for (int i = (n4 << 2) + threadIdx.x; i < n; i += 1024) {
        uint32_t w = ebuf[abase + i];
        atomicAdd(&whist[wid][(w & 0xFFFFu) >> 13], 1); atomicAdd(&dh[w >> 16], 1);
    }
    __syncthreads();
    if (threadIdx.x == 0) {
        int run = 0;
        for (int b = 0; b < 8; b++) {
            bb[b] = run;
            sstart[c * 9 + b] = obase + run;
            int tot = 0;
            for (int w2 = 0; w2 < 16; w2++) tot += whist[w2][b];
            run += tot;
        }
        sstart[c * 9 + 8] = obase + run;
    }
    __syncthreads();
    if (threadIdx.x < 8) {
        int b = threadIdx.x;
        int run = obase + bb[b];
        for (int w2 = 0; w2 < 16; w2++) { wcur[w2][b] = run; run += whist[w2][b]; }
    }
    for (int i = threadIdx.x; i < DSZ; i += 1024) {
        int d = dh[i];
        if (d) atomicAdd(&deg[t * DSZ + i], d);
    }
    __syncthreads();
    for (int i = threadIdx.x; i < n4; i += 1024) {
        uint4 w = eb4[i];
        int pos;
        pos = atomicAdd(&wcur[wid][(w.x & 0xFFFFu) >> 13], 1); sorted[pos] = w.x;
        pos = atomicAdd(&wcur[wid][(w.y & 0xFFFFu) >> 13], 1); sorted[pos] = w.y;
        pos = atomicAdd(&wcur[wid][(w.z & 0xFFFFu) >> 13], 1); sorted[pos] = w.z;
        pos = atomicAdd(&wcur[wid][(w.w & 0xFFFFu) >> 13], 1); sorted[pos] = w.w;
    }
    for (int i = (n4 << 2) + threadIdx.x; i < n; i += 1024) {
        uint32_t w = ebuf[abase + i];
        int pos = atomicAdd(&wcur[wid][(w & 0xFFFFu) >> 13], 1); sorted[pos] = w;
    }
}

__global__ void dis_kernel(const int* __restrict__ deg, const float* __restrict__ x0,
                           float* __restrict__ dis, float* __restrict__ z0) {
    int v = blockIdx.x * 1024 + threadIdx.x;
    if (v < NN) {
        float d = rsqrtf((float)(deg[v] + 1));   // +1 self loop
        dis[v] = d;
        z0[v] = x0[v] * d;
    }
}

// ---------------- per-layer: scatter + last-block-of-tile combine ---------
// Block = chunk (t of 8192 dst, q of 62500 src). LDS 64KB -> 2 blocks/CU,
// 32 waves/CU (2x every prior LDS design; tests the latency-bound theory).
// After flushing its partial, the 8th block of tile t combines the tile
// (threadfence + per-tile counter): 49 dispatches instead of 98, hp stays
// L2-hot, combine overlaps other tiles' scatter.
__global__ __launch_bounds__(1024, 8) void layer_kernel(
        const int* __restrict__ sstart, const uint32_t* __restrict__ eb,
        const float* __restrict__ zin, const float* __restrict__ dis,
        const float* __restrict__ x0, const float* __restrict__ w,
        int li, int act, float* __restrict__ zout, int* __restrict__ out,
        float* __restrict__ hp, int* __restrict__ tilecnt) {
    __shared__ float acc[DSZ];            // 32KB
    __shared__ float zt[8192];            // 32KB
    __shared__ int lastf;
    int c = blockIdx.x;
    int tid = threadIdx.x;
    int t = c >> 3, q = c & 7;
    for (int i = tid; i < DSZ; i += 1024) acc[i] = 0.f;
    const float4* zin4 = (const float4*)zin;
    float4* zt4 = (float4*)zt;
    int ob4 = (q * OCTW) >> 2;            // octant float4 base (62500%4==0)
    float4 r0 = zin4[ob4 + tid];          // k=0 prefetch (cnt4=2048: both valid)
    float4 r1 = zin4[ob4 + 1024 + tid];
    int base9 = c * 9;
    int lo = sstart[base9];
    for (int k = 0; k < 8; k++) {
        int hi = sstart[base9 + k + 1];
        int cnt4 = min(2048, 15625 - (k << 11));
        __syncthreads();                  // prev subchunk's zt readers done
        if (tid < cnt4) zt4[tid] = r0;
        if (1024 + tid < cnt4) zt4[1024 + tid] = r1;
        if (k < 7) {                      // issue next subchunk's loads early
            int nb4 = ob4 + ((k + 1) << 11);
            int nc4 = min(2048, 15625 - ((k + 1) << 11));
            if (tid < nc4) r0 = zin4[nb4 + tid];
            if (1024 + tid < nc4) r1 = zin4[nb4 + 1024 + tid];
        }
        __syncthreads();                  // zt visible
        int koff = k << 13;
        for (int i = lo + tid; i < hi; i += 1024) {
            uint32_t wv = eb[i];
            atomicAdd(&acc[wv >> 16], zt[(int)(wv & 0xFFFFu) - koff]);
        }
        lo = hi;
    }
    __syncthreads();
    // flush partial to hp
    float4* dst4 = (float4*)(hp + (size_t)q * HPST + (size_t)t * DSZ);
    const float4* a4 = (const float4*)acc;
    for (int i = tid; i < DSZ / 4; i += 1024) dst4[i] = a4[i];
    __threadfence();                      // release: hp visible before count
    __syncthreads();
    if (tid == 0) lastf = (atomicAdd(&tilecnt[t], 1) == NQ - 1);
    __syncthreads();
    if (!lastf) return;
    __threadfence();                      // acquire: see sibling blocks' hp
    // combine tile t: 8 partials + self loop + epilogue
    const float4* hp4 = (const float4*)hp;
    const float4* dis4 = (const float4*)dis;
    const float4* x04 = (const float4*)x0;
    float4* zout4 = (float4*)zout;
    int4* out4 = (int4*)out;
    int tb4 = t * (DSZ / 4);
    int cnt = min(DSZ / 4, NF4 - tb4);    // last tile: 72 float4
    float wl = w[li];
    for (int j = tid; j < cnt; j += 1024) {
        int v4 = tb4 + j;
        float4 s = zin4[v4];                            // self loop
        #pragma unroll
        for (int qq = 0; qq < NQ; qq++) {
            float4 hq = hp4[(size_t)qq * (HPST / 4) + v4];
            s.x += hq.x; s.y += hq.y; s.z += hq.z; s.w += hq.w;
        }
        float4 dv = dis4[v4];
        float4 xv = x04[v4];
        float y0 = (0.7f * dv.x * s.x + 0.3f * xv.x) * wl;
        float y1 = (0.7f * dv.y * s.y + 0.3f * xv.y) * wl;
        float y2 = (0.7f * dv.z * s.z + 0.3f * xv.z) * wl;
        float y3 = (0.7f * dv.w * s.w + 0.3f * xv.w) * wl;
        if (act == 4) {
            int4 o;
            o.x = (int)(500000.f / (1.f + expf(-y0)));
            o.y = (int)(500000.f / (1.f + expf(-y1)));
            o.z = (int)(500000.f / (1.f + expf(-y2)));
            o.w = (int)(500000.f / (1.f + expf(-y3)));
            out4[v4] = o;
        } else {
            float r0v, r1v, r2v, r3v;
            if (act == 0)      { r0v = y0; r1v = y1; r2v = y2; r3v = y3; }
            else if (act == 1) { r0v = fmaxf(y0, 0.f); r1v = fmaxf(y1, 0.f);
                                 r2v = fmaxf(y2, 0.f); r3v = fmaxf(y3, 0.f); }
            else if (act == 2) { r0v = (y0 > 0.f) ? y0 : 0.01f * y0;
                                 r1v = (y1 > 0.f) ? y1 : 0.01f * y1;
                                 r2v = (y2 > 0.f) ? y2 : 0.01f * y2;
                                 r3v = (y3 > 0.f) ? y3 : 0.01f * y3; }
            else               { r0v = 1.f / (1.f + expf(-y0)); r1v = 1.f / (1.f + expf(-y1));
                                 r2v = 1.f / (1.f + expf(-y2)); r3v = 1.f / (1.f + expf(-y3)); }
            float4 zo;
            zo.x = dv.x * r0v; zo.y = dv.y * r1v; zo.z = dv.z * r2v; zo.w = dv.w * r3v;
            zout4[v4] = zo;
        }
    }
}

// ---------------- launch ----------------
extern "C" void kernel_launch(void* const* d_in, const int* in_sizes, int n_in,
                              void* d_out, int out_size, void* d_ws, size_t ws_size,
                              hipStream_t stream) {
    const float* x0  = (const float*)d_in[0];
    const float* w   = (const float*)d_in[1];
    const int*   adj = (const int*)d_in[2];             // int32 (jax demotes int64)
    const int*   src = adj;
    const int*   dst = adj + NE;
    int* out = (int*)d_out;

    uintptr_t p = (uintptr_t)d_ws;
    auto alloc = [&](size_t bytes) -> void* {
        p = (p + 255) & ~(uintptr_t)255;
        void* r = (void*)p;
        p += bytes;
        return r;
    };
    float* dis     = (float*)alloc((size_t)NN * 4);
    float* z0      = (float*)alloc((size_t)NN * 4);
    float* z1      = (float*)alloc((size_t)NN * 4);
    int*   deg     = (int*)alloc((size_t)HPST * 4);               // 2MB
    int*   bcnt    = (int*)alloc((size_t)NCH * 4);
    int*   cbase   = (int*)alloc((size_t)(NCH + 1) * 4);
    int*   sstart  = (int*)alloc((size_t)NCH * 9 * 4);
    int*   tilecnt = (int*)alloc((size_t)49 * NTILE * 4);
    uint32_t* slots  = (uint32_t*)alloc((size_t)NCH * SLOT * 4);  // 67.7MB
    uint32_t* sorted = (uint32_t*)alloc((size_t)NE * 4);          // 64MB
    float* hp      = (float*)alloc((size_t)NQ * HPST * 4);        // 16.25MB
    (void)ws_size;

    hipMemsetAsync(bcnt, 0, (size_t)NCH * 4, stream);
    hipMemsetAsync(deg, 0, (size_t)HPST * 4, stream);
    hipMemsetAsync(tilecnt, 0, (size_t)49 * NTILE * 4, stream);

    partition_kernel<<<NPB, 1024, 0, stream>>>((const int4*)src, (const int4*)dst, bcnt, slots);
    cbase_scan<<<1, 64, 0, stream>>>(bcnt, cbase);
    subsort_kernel<<<NCH, 1024, 0, stream>>>(bcnt, cbase, slots, sorted, sstart, deg);
    dis_kernel<<<(NN + 1023) / 1024, 1024, 0, stream>>>(deg, x0, dis, z0);

    float* zbuf[2] = {z0, z1};
    for (int i = 0; i < 49; i++) {
        int act;
        if (i == 0)            act = 0;
        else if (i == 48)      act = 4;
        else if (i % 10 == 1)  act = 2;                 // leaky {1,11,21,31,41}
        else if (i % 10 == 4)  act = 3;                 // sigmoid {4,14,24,34,44}
        else                   act = 1;                 // relu
        layer_kernel<<<NCH, 1024, 0, stream>>>(sstart, sorted, zbuf[i & 1], dis, x0, w,
                                               i, act, zbuf[(i + 1) & 1], out,
                                               hp, tilecnt + i * NTILE);
    }
}

// Round 9
// 5575.776 us; speedup vs baseline: 3.4313x; 3.4313x over previous
//
#include <hip/hip_runtime.h>
#include <math.h>

#define NN 500000
#define NE 16000000
#define NBKT 977                  // ceil(NN/512): bucket = dst >> 9
#define PB 65536                  // edges per partition block
#define NPB ((NE + PB - 1) / PB)  // 245
#define BKT_CAP 17920             // mean 16384, +8.5 sigma
#define SLOTB 17920               // fixed slot per bucket (== cap, 16-mult)

// ---------------- phase 1: partition edges into fixed bucket slots --------
// No hist/scan prepass (r7-proven): bucket b owns ebuf[b*SLOTB ...).
// word = (dst&511)<<19 | src  (src < 2^19, dlo < 2^9).
__global__ __launch_bounds__(1024) void partition_kernel(const int4* __restrict__ src4,
                                                         const int4* __restrict__ dst4,
                                                         int* __restrict__ bcnt,
                                                         int* __restrict__ ebuf) {
    __shared__ int lh[NBKT];
    for (int i = threadIdx.x; i < NBKT; i += 1024) lh[i] = 0;
    __syncthreads();
    long base4 = (long)blockIdx.x * (PB / 4);
    for (int k = 0; k < PB / 4; k += 1024) {
        long i4 = base4 + k + threadIdx.x;
        if (i4 < NE / 4) {
            int4 d = dst4[i4];
            atomicAdd(&lh[d.x >> 9], 1);
            atomicAdd(&lh[d.y >> 9], 1);
            atomicAdd(&lh[d.z >> 9], 1);
            atomicAdd(&lh[d.w >> 9], 1);
        }
    }
    __syncthreads();
    for (int i = threadIdx.x; i < NBKT; i += 1024) {
        int c = lh[i];
        if (c) lh[i] = atomicAdd(&bcnt[i], c);   // reserve run; lh = block cursor
    }
    __syncthreads();
    for (int k = 0; k < PB / 4; k += 1024) {
        long i4 = base4 + k + threadIdx.x;
        if (i4 < NE / 4) {
            int4 d = dst4[i4];
            int4 s = src4[i4];
            int b, rel;
            b = d.x >> 9; rel = atomicAdd(&lh[b], 1);
            if (rel < SLOTB) ebuf[(long)b * SLOTB + rel] = ((d.x & 511) << 19) | s.x;
            b = d.y >> 9; rel = atomicAdd(&lh[b], 1);
            if (rel < SLOTB) ebuf[(long)b * SLOTB + rel] = ((d.y & 511) << 19) | s.y;
            b = d.z >> 9; rel = atomicAdd(&lh[b], 1);
            if (rel < SLOTB) ebuf[(long)b * SLOTB + rel] = ((d.z & 511) << 19) | s.z;
            b = d.w >> 9; rel = atomicAdd(&lh[b], 1);
            if (rel < SLOTB) ebuf[(long)b * SLOTB + rel] = ((d.w & 511) << 19) | s.w;
        }
    }
}

// ---------------- phase 2: per-bucket CSR build (in slot, compacted) ------
// LDS counting sort by dst (r2/r4-proven); writes csr back compacted into
// the bucket's slot; emits rp/re (begin/end), dis, z0. LDS ~143KB.
__global__ __launch_bounds__(512) void bucket_csr(const int* __restrict__ bcnt,
                                                  int* __restrict__ ebuf,   // == csr, in place
                                                  int* __restrict__ rp,
                                                  int* __restrict__ re,
                                                  float* __restrict__ dis,
                                                  const float* __restrict__ x0,
                                                  float* __restrict__ z0) {
    __shared__ int eds[BKT_CAP];
    __shared__ int outb[BKT_CAP];
    __shared__ int cnt[512];
    __shared__ int scn[512];
    int b = blockIdx.x;
    long ebase = (long)b * SLOTB;
    int nb = bcnt[b];
    if (nb > BKT_CAP) nb = BKT_CAP;       // p ~ 1e-17; guards LDS
    for (int i = threadIdx.x; i < nb; i += 512) eds[i] = ebuf[ebase + i];
    cnt[threadIdx.x] = 0;
    __syncthreads();
    for (int i = threadIdx.x; i < nb; i += 512) atomicAdd(&cnt[eds[i] >> 19], 1);
    __syncthreads();
    int my = cnt[threadIdx.x];
    scn[threadIdx.x] = my;
    __syncthreads();
    for (int off = 1; off < 512; off <<= 1) {
        int t = (threadIdx.x >= off) ? scn[threadIdx.x - off] : 0;
        __syncthreads();
        scn[threadIdx.x] += t;
        __syncthreads();
    }
    int excl = scn[threadIdx.x] - my;
    int v = b * 512 + threadIdx.x;
    if (v < NN) {
        rp[v] = (int)ebase + excl;
        re[v] = (int)ebase + excl + my;
        float dv = rsqrtf((float)(my + 1));         // +1 self loop
        dis[v] = dv;
        z0[v] = x0[v] * dv;
    }
    __syncthreads();
    cnt[threadIdx.x] = excl;                        // reuse as running cursor
    __syncthreads();
    for (int i = threadIdx.x; i < nb; i += 512) {
        int p = eds[i];
        int pos = atomicAdd(&cnt[p >> 19], 1);
        outb[pos] = p & 0x7FFFF;                    // scatter in LDS
    }
    __syncthreads();
    for (int i = threadIdx.x; i < nb; i += 512) ebuf[ebase + i] = outb[i];  // coalesced
}

// ---------------- per-layer SpMV (CSR-vector, 8 lanes/row) ----------------
// h[v] = dis[v]*(sum z[src] + z[v]);  y = (0.7h + 0.3 x0)*w; act.
// csr loads are NON-TEMPORAL: 64MB/layer of edge words would otherwise
// thrash the 2MB z array out of the 32MB aggregate L2 between its ~512
// touches/line; nt keeps z L2-resident -> gather latency L3 -> L2.
// Gathers batched 4-wide (MLP). Summation order == r1/r2 (bit-identical).
__global__ __launch_bounds__(256) void layer_kernel(
        const int* __restrict__ rp, const int* __restrict__ re,
        const int* __restrict__ csr,
        const float* __restrict__ zin, const float* __restrict__ dis,
        const float* __restrict__ x0, const float* __restrict__ w,
        int li, int act, float* __restrict__ zout, int* __restrict__ out) {
    int tid = blockIdx.x * 256 + threadIdx.x;
    int v = tid >> 3;                                   // 8 lanes per row; grid exact
    int lane = threadIdx.x & 7;
    int beg = rp[v];
    int end = re[v];
    float s = 0.f;
    int j = beg + lane;
    for (; j + 24 < end; j += 32) {
        int c0 = __builtin_nontemporal_load(csr + j);
        int c1 = __builtin_nontemporal_load(csr + j + 8);
        int c2 = __builtin_nontemporal_load(csr + j + 16);
        int c3 = __builtin_nontemporal_load(csr + j + 24);
        float z0 = zin[c0];
        float z1 = zin[c1];
        float z2 = zin[c2];
        float z3 = zin[c3];
        s += z0; s += z1; s += z2; s += z3;
    }
    for (; j < end; j += 8) s += zin[__builtin_nontemporal_load(csr + j)];
    s += __shfl_xor(s, 1);
    s += __shfl_xor(s, 2);
    s += __shfl_xor(s, 4);
    if (lane != 0) return;
    s += zin[v];                                        // self loop
    float h = dis[v] * s;
    float comb = 0.7f * h + 0.3f * x0[v];
    float y = comb * w[li];
    if (act == 4) {
        float sg = 1.f / (1.f + expf(-y));
        out[v] = (int)(500000.f * sg);
        return;
    }
    float r;
    if (act == 0)      r = y;
    else if (act == 1) r = fmaxf(y, 0.f);
    else if (act == 2) r = (y > 0.f) ? y : 0.01f * y;
    else               r = 1.f / (1.f + expf(-y));      // sigmoid
    zout[v] = dis[v] * r;
}

// ---------------- launch ----------------
extern "C" void kernel_launch(void* const* d_in, const int* in_sizes, int n_in,
                              void* d_out, int out_size, void* d_ws, size_t ws_size,
                              hipStream_t stream) {
    const float* x0  = (const float*)d_in[0];
    const float* w   = (const float*)d_in[1];
    const int*   adj = (const int*)d_in[2];             // int32 (jax demotes int64)
    const int*   src = adj;
    const int*   dst = adj + NE;
    int* out = (int*)d_out;

    uintptr_t p = (uintptr_t)d_ws;
    auto alloc = [&](size_t bytes) -> void* {
        p = (p + 255) & ~(uintptr_t)255;
        void* r = (void*)p;
        p += bytes;
        return r;
    };
    float* dis  = (float*)alloc((size_t)NN * 4);
    int*   rp   = (int*)alloc((size_t)NN * 4);
    int*   re   = (int*)alloc((size_t)NN * 4);
    float* z0   = (float*)alloc((size_t)NN * 4);
    float* z1   = (float*)alloc((size_t)NN * 4);
    int*   bcnt = (int*)alloc((size_t)NBKT * 4);
    int*   csr  = (int*)alloc((size_t)NBKT * SLOTB * 4);   // 70MB slots, rebuilt in place
    (void)ws_size;

    hipMemsetAsync(bcnt, 0, (size_t)NBKT * 4, stream);

    partition_kernel<<<NPB, 1024, 0, stream>>>((const int4*)src, (const int4*)dst, bcnt, csr);
    bucket_csr<<<NBKT, 512, 0, stream>>>(bcnt, csr, rp, re, dis, x0, z0);

    float* zbuf[2] = {z0, z1};
    const int LB = (NN * 8) / 256;                      // 15625, exact
    for (int i = 0; i < 49; i++) {
        int act;
        if (i == 0)            act = 0;
        else if (i == 48)      act = 4;
        else if (i % 10 == 1)  act = 2;                 // leaky {1,11,21,31,41}
        else if (i % 10 == 4)  act = 3;                 // sigmoid {4,14,24,34,44}
        else                   act = 1;                 // relu
        layer_kernel<<<LB, 256, 0, stream>>>(rp, re, csr, zbuf[i & 1], dis, x0, w,
                                             i, act, zbuf[(i + 1) & 1], out);
    }
}